// Round 5
// baseline (1231.129 us; speedup 1.0000x reference)
//
#include <hip/hip_runtime.h>

#define CIN    32
#define COUT   32
#define KMAX   27
#define SCAN_B 2048

__device__ __forceinline__ unsigned short f2bf(float f) {
    unsigned u = __float_as_uint(f);
    return (unsigned short)((u + 0x7fffu + ((u >> 16) & 1u)) >> 16);   // RNE
}
__device__ __forceinline__ float lof(unsigned u) { return __uint_as_float(u << 16); }
__device__ __forceinline__ float hif(unsigned u) { return __uint_as_float(u & 0xffff0000u); }

// ---- pack weights to bf16 pairs: uint idx = ((k*4+j)*32 + o)*4 + dj,
//      holds channels (8j+2dj, 8j+2dj+1) for output o. ----
__global__ void kb_pack(const float* __restrict__ w, unsigned* __restrict__ wB, int total)
{
    int idx = blockIdx.x * blockDim.x + threadIdx.x;
    if (idx >= total) return;
    int dj = idx & 3, o = (idx >> 2) & 31, j = (idx >> 7) & 3, k = idx >> 9;
    int i0 = 8 * j + 2 * dj;
    unsigned lo = f2bf(w[(k * CIN + i0) * COUT + o]);
    unsigned hi = f2bf(w[(k * CIN + i0 + 1) * COUT + o]);
    wB[idx] = lo | (hi << 16);
}

// ---- per-row k-mask (injective within k => one bit per (row,k)) ----
__global__ void kb_mask(const int* __restrict__ scatter, unsigned* __restrict__ mask,
                        int npair, int M)
{
    int p = blockIdx.x * blockDim.x + threadIdx.x;
    int k = blockIdx.y;
    if (p >= npair) return;
    int s = scatter[(size_t)k * npair + p];
    if (s < M) atomicOr(&mask[s], 1u << k);
}

// ---- scan level 1: per-block sums of popcount(mask) ----
__global__ void kb_scan1(const unsigned* __restrict__ mask, int* __restrict__ part, int n)
{
    __shared__ int red[256];
    int base = blockIdx.x * SCAN_B;
    int sum = 0;
    for (int i = threadIdx.x; i < SCAN_B; i += 256) {
        int idx = base + i;
        sum += (idx < n) ? __popc(mask[idx]) : 0;
    }
    red[threadIdx.x] = sum;
    __syncthreads();
    for (int s = 128; s > 0; s >>= 1) {
        if (threadIdx.x < s) red[threadIdx.x] += red[threadIdx.x + s];
        __syncthreads();
    }
    if (threadIdx.x == 0) part[blockIdx.x] = red[0];
}

// ---- scan level 2: single-block parallel exclusive scan of part[0..nb), nb<=2048 ----
__global__ void kb_scan2(int* __restrict__ part, int nb, int* __restrict__ total_out)
{
    __shared__ int a[2048], b[2048];
    int t = threadIdx.x;
    for (int i = t; i < 2048; i += 1024) a[i] = (i < nb) ? part[i] : 0;
    __syncthreads();
    int* src = a; int* dst = b;
    for (int ofs = 1; ofs < 2048; ofs <<= 1) {
        for (int i = t; i < 2048; i += 1024)
            dst[i] = (i >= ofs) ? src[i] + src[i - ofs] : src[i];
        __syncthreads();
        int* tmp = src; src = dst; dst = tmp;
    }
    for (int i = t; i < 2048; i += 1024)
        if (i < nb) part[i] = (i == 0) ? 0 : src[i - 1];
    if (t == 0) *total_out = src[nb - 1];
}

// ---- scan level 3: block-local exclusive scan of popcounts + block offset ----
__global__ void kb_scan3(const unsigned* __restrict__ mask, const int* __restrict__ part,
                         int* __restrict__ row_start, int n)
{
    __shared__ int ts[256];
    int base = blockIdx.x * SCAN_B;
    int v[8];
    int sum = 0;
#pragma unroll
    for (int j = 0; j < 8; ++j) {
        int idx = base + threadIdx.x * 8 + j;
        v[j] = (idx < n) ? __popc(mask[idx]) : 0;
        sum += v[j];
    }
    ts[threadIdx.x] = sum;
    __syncthreads();
    for (int ofs = 1; ofs < 256; ofs <<= 1) {
        int add = (threadIdx.x >= ofs) ? ts[threadIdx.x - ofs] : 0;
        __syncthreads();
        ts[threadIdx.x] += add;
        __syncthreads();
    }
    int excl = (threadIdx.x == 0) ? 0 : ts[threadIdx.x - 1];
    excl += part[blockIdx.x];
#pragma unroll
    for (int j = 0; j < 8; ++j) {
        int idx = base + threadIdx.x * 8 + j;
        if (idx < n) row_start[idx] = excl;
        excl += v[j];
    }
}

// ---- build CSR entries: slot is deterministic (k-ascending within row) ----
__global__ void kb_build(const int* __restrict__ gather, const int* __restrict__ scatter,
                         const unsigned* __restrict__ mask, const int* __restrict__ row_start,
                         int* __restrict__ list, int npair, int M)
{
    int p = blockIdx.x * blockDim.x + threadIdx.x;
    int k = blockIdx.y;
    if (p >= npair) return;
    int s = scatter[(size_t)k * npair + p];
    if (s >= M) return;
    int g = gather[(size_t)k * npair + p];
    int slot = row_start[s] + __popc(mask[s] & ((1u << k) - 1u));
    list[slot] = (k << 18) | g;
}

// ---- main: half-wave per output row, write-once, no barriers/atomics ----
__global__ __launch_bounds__(256)
void kb_main(const float* __restrict__ feat, const uint4* __restrict__ wB,
             const int* __restrict__ row_start, const int* __restrict__ list,
             float* __restrict__ out, int M)
{
    const int lane = threadIdx.x & 31;
    int h  = (blockIdx.x * blockDim.x + threadIdx.x) >> 5;
    int nh = (gridDim.x * blockDim.x) >> 5;
    for (int m = h; m < M; m += nh) {
        int e0 = row_start[m], e1 = row_start[m + 1];
        float a0 = 0.f, a1 = 0.f, a2 = 0.f, a3 = 0.f;
        for (int e = e0; e < e1; ++e) {
            int pk = list[e];
            int k = pk >> 18, g = pk & 0x3FFFF;
            const float4* fr = (const float4*)(feat + (size_t)g * CIN);
            const uint4*  wr = wB + (k * 128 + lane);
            uint4 wq; float4 fA, fB;
            wq = wr[0];  fA = fr[0]; fB = fr[1];
            a0 = fmaf(fA.x, lof(wq.x), a0); a0 = fmaf(fA.y, hif(wq.x), a0);
            a0 = fmaf(fA.z, lof(wq.y), a0); a0 = fmaf(fA.w, hif(wq.y), a0);
            a0 = fmaf(fB.x, lof(wq.z), a0); a0 = fmaf(fB.y, hif(wq.z), a0);
            a0 = fmaf(fB.z, lof(wq.w), a0); a0 = fmaf(fB.w, hif(wq.w), a0);
            wq = wr[32]; fA = fr[2]; fB = fr[3];
            a1 = fmaf(fA.x, lof(wq.x), a1); a1 = fmaf(fA.y, hif(wq.x), a1);
            a1 = fmaf(fA.z, lof(wq.y), a1); a1 = fmaf(fA.w, hif(wq.y), a1);
            a1 = fmaf(fB.x, lof(wq.z), a1); a1 = fmaf(fB.y, hif(wq.z), a1);
            a1 = fmaf(fB.z, lof(wq.w), a1); a1 = fmaf(fB.w, hif(wq.w), a1);
            wq = wr[64]; fA = fr[4]; fB = fr[5];
            a2 = fmaf(fA.x, lof(wq.x), a2); a2 = fmaf(fA.y, hif(wq.x), a2);
            a2 = fmaf(fA.z, lof(wq.y), a2); a2 = fmaf(fA.w, hif(wq.y), a2);
            a2 = fmaf(fB.x, lof(wq.z), a2); a2 = fmaf(fB.y, hif(wq.z), a2);
            a2 = fmaf(fB.z, lof(wq.w), a2); a2 = fmaf(fB.w, hif(wq.w), a2);
            wq = wr[96]; fA = fr[6]; fB = fr[7];
            a3 = fmaf(fA.x, lof(wq.x), a3); a3 = fmaf(fA.y, hif(wq.x), a3);
            a3 = fmaf(fA.z, lof(wq.y), a3); a3 = fmaf(fA.w, hif(wq.y), a3);
            a3 = fmaf(fB.x, lof(wq.z), a3); a3 = fmaf(fB.y, hif(wq.z), a3);
            a3 = fmaf(fB.z, lof(wq.w), a3); a3 = fmaf(fB.w, hif(wq.w), a3);
        }
        out[(size_t)m * COUT + lane] = (a0 + a1) + (a2 + a3);
    }
}

// ---- fallback (R1): atomic scatter ----
__global__ __launch_bounds__(256, 4)
void spconv_scatter(const float* __restrict__ feat, const float* __restrict__ weight,
                    const int* __restrict__ gather, const int* __restrict__ scatter,
                    float* __restrict__ out, int npair, int M)
{
    const int k = blockIdx.y;
    const int lane = threadIdx.x & 31;
    const int sub = threadIdx.x >> 5;
    const int pairs_per_blk = blockDim.x >> 5;
    const float* wk = weight + (size_t)k * (CIN * COUT);
    float w[CIN];
#pragma unroll
    for (int i = 0; i < CIN; ++i) w[i] = wk[i * COUT + lane];
    const int* gk = gather + (size_t)k * npair;
    const int* sk = scatter + (size_t)k * npair;
    for (int p = blockIdx.x * pairs_per_blk + sub; p < npair; p += gridDim.x * pairs_per_blk) {
        int s = sk[p];
        if (s >= M) continue;
        int g = gk[p];
        const float4* fr = (const float4*)(feat + (size_t)g * CIN);
        float a = 0.f;
#pragma unroll
        for (int c = 0; c < 8; ++c) {
            float4 f4 = fr[c];
            a = fmaf(f4.x, w[4*c+0], a); a = fmaf(f4.y, w[4*c+1], a);
            a = fmaf(f4.z, w[4*c+2], a); a = fmaf(f4.w, w[4*c+3], a);
        }
        atomicAdd(&out[(size_t)s * COUT + lane], a);
    }
}

extern "C" void kernel_launch(void* const* d_in, const int* in_sizes, int n_in,
                              void* d_out, int out_size, void* d_ws, size_t ws_size,
                              hipStream_t stream)
{
    const float* feat    = (const float*)d_in[0];
    const float* weight  = (const float*)d_in[1];
    const int*   gather  = (const int*)d_in[2];
    const int*   scatter = (const int*)d_in[3];
    float*       out     = (float*)d_out;

    const int K     = in_sizes[1] / (CIN * COUT);   // 27
    const int npair = in_sizes[2] / K;              // 150000
    const int M     = out_size / COUT;              // num_out (~2.13M)
    const int NB    = (M + SCAN_B - 1) / SCAN_B;    // scan blocks (~1041)

    // workspace layout
    uintptr_t base = (uintptr_t)d_ws;
    auto align16 = [](uintptr_t p) { return (p + 15) & ~(uintptr_t)15; };
    uintptr_t p_mask = align16(base);                              // M uints
    uintptr_t p_rs   = align16(p_mask + (size_t)M * 4);            // M+1 ints
    uintptr_t p_part = align16(p_rs + ((size_t)M + 1) * 4);        // 2048 ints
    uintptr_t p_wB   = align16(p_part + 2048 * 4);                 // K*512 uints
    uintptr_t p_list = align16(p_wB + (size_t)K * 512 * 4);        // K*npair ints
    uintptr_t p_end  = p_list + (size_t)K * npair * 4;

    if (p_end - base > ws_size || NB > 2048 || K > KMAX) {
        // fallback: atomic scatter
        hipMemsetAsync(d_out, 0, (size_t)out_size * sizeof(float), stream);
        dim3 grid(160, K);
        spconv_scatter<<<grid, 256, 0, stream>>>(feat, weight, gather, scatter, out, npair, M);
        return;
    }

    unsigned* mask      = (unsigned*)p_mask;
    int*      row_start = (int*)p_rs;
    int*      part      = (int*)p_part;
    unsigned* wB        = (unsigned*)p_wB;
    int*      list      = (int*)p_list;

    hipMemsetAsync(mask, 0, (size_t)M * 4, stream);

    kb_pack<<<(K * 512 + 255) / 256, 256, 0, stream>>>(weight, wB, K * 512);

    dim3 gp((npair + 255) / 256, K);
    kb_mask<<<gp, 256, 0, stream>>>(scatter, mask, npair, M);

    kb_scan1<<<NB, 256, 0, stream>>>(mask, part, M);
    kb_scan2<<<1, 1024, 0, stream>>>(part, NB, row_start + M);   // also writes total
    kb_scan3<<<NB, 256, 0, stream>>>(mask, part, row_start, M);

    kb_build<<<gp, 256, 0, stream>>>(gather, scatter, mask, row_start, list, npair, M);

    // write-once main: every output row has >=1 contributor, no memset of d_out
    kb_main<<<4096, 256, 0, stream>>>(feat, (const uint4*)wB, row_start, list, out, M);
}

// Round 6
// 711.161 us; speedup vs baseline: 1.7312x; 1.7312x over previous
//
#include <hip/hip_runtime.h>

#define CIN    32
#define COUT   32
#define KMAX   27
#define SCAN_B 2048

typedef _Float16 h2_t __attribute__((ext_vector_type(2)));

__device__ __forceinline__ float dot2(unsigned f, unsigned w, float a)
{
#if __has_builtin(__builtin_amdgcn_fdot2)
    return __builtin_amdgcn_fdot2(__builtin_bit_cast(h2_t, f),
                                  __builtin_bit_cast(h2_t, w), a, false);
#else
    h2_t ff = __builtin_bit_cast(h2_t, f), ww = __builtin_bit_cast(h2_t, w);
    return a + (float)ff.x * (float)ww.x + (float)ff.y * (float)ww.y;
#endif
}

__device__ __forceinline__ unsigned f2h2(float a, float b)
{
    unsigned short ua = __builtin_bit_cast(unsigned short, (_Float16)a);
    unsigned short ub = __builtin_bit_cast(unsigned short, (_Float16)b);
    return (unsigned)ua | ((unsigned)ub << 16);
}

// ---- pack weights to f16 pairs: uint idx = ((k*4+j)*32 + o)*4 + dj holds
//      input channels (8j+2dj, 8j+2dj+1) for output channel o ----
__global__ void kb_pack(const float* __restrict__ w, unsigned* __restrict__ wH, int total)
{
    int idx = blockIdx.x * blockDim.x + threadIdx.x;
    if (idx >= total) return;
    int dj = idx & 3, o = (idx >> 2) & 31, j = (idx >> 7) & 3, k = idx >> 9;
    int i0 = 8 * j + 2 * dj;
    wH[idx] = f2h2(w[(k * CIN + i0) * COUT + o], w[(k * CIN + i0 + 1) * COUT + o]);
}

// ---- pack features to f16 pairs: uint idx = g*16 + c holds feat[g][2c], feat[g][2c+1] ----
__global__ void kf_pack(const float* __restrict__ f, unsigned* __restrict__ fH, int total)
{
    int idx = blockIdx.x * blockDim.x + threadIdx.x;
    if (idx >= total) return;
    const float2 v = ((const float2*)f)[idx];
    fH[idx] = f2h2(v.x, v.y);
}

// ---- per-row k-mask (injective within k => one bit per (row,k)) ----
__global__ void kb_mask(const int* __restrict__ scatter, unsigned* __restrict__ mask,
                        int npair, int M)
{
    int p = blockIdx.x * blockDim.x + threadIdx.x;
    int k = blockIdx.y;
    if (p >= npair) return;
    int s = scatter[(size_t)k * npair + p];
    if (s < M) atomicOr(&mask[s], 1u << k);
}

// ---- scan level 1: per-block sums of popcount(mask) ----
__global__ void kb_scan1(const unsigned* __restrict__ mask, int* __restrict__ part, int n)
{
    __shared__ int red[256];
    int base = blockIdx.x * SCAN_B;
    int sum = 0;
    for (int i = threadIdx.x; i < SCAN_B; i += 256) {
        int idx = base + i;
        sum += (idx < n) ? __popc(mask[idx]) : 0;
    }
    red[threadIdx.x] = sum;
    __syncthreads();
    for (int s = 128; s > 0; s >>= 1) {
        if (threadIdx.x < s) red[threadIdx.x] += red[threadIdx.x + s];
        __syncthreads();
    }
    if (threadIdx.x == 0) part[blockIdx.x] = red[0];
}

// ---- scan level 2: single-block exclusive scan of part[0..nb), nb<=2048 ----
__global__ void kb_scan2(int* __restrict__ part, int nb, int* __restrict__ total_out)
{
    __shared__ int a[2048], b[2048];
    int t = threadIdx.x;
    for (int i = t; i < 2048; i += 1024) a[i] = (i < nb) ? part[i] : 0;
    __syncthreads();
    int* src = a; int* dst = b;
    for (int ofs = 1; ofs < 2048; ofs <<= 1) {
        for (int i = t; i < 2048; i += 1024)
            dst[i] = (i >= ofs) ? src[i] + src[i - ofs] : src[i];
        __syncthreads();
        int* tmp = src; src = dst; dst = tmp;
    }
    for (int i = t; i < 2048; i += 1024)
        if (i < nb) part[i] = (i == 0) ? 0 : src[i - 1];
    if (t == 0) *total_out = src[nb - 1];
}

// ---- scan level 3: block-local exclusive scan of popcounts + block offset ----
__global__ void kb_scan3(const unsigned* __restrict__ mask, const int* __restrict__ part,
                         int* __restrict__ row_start, int n)
{
    __shared__ int ts[256];
    int base = blockIdx.x * SCAN_B;
    int v[8];
    int sum = 0;
#pragma unroll
    for (int j = 0; j < 8; ++j) {
        int idx = base + threadIdx.x * 8 + j;
        v[j] = (idx < n) ? __popc(mask[idx]) : 0;
        sum += v[j];
    }
    ts[threadIdx.x] = sum;
    __syncthreads();
    for (int ofs = 1; ofs < 256; ofs <<= 1) {
        int add = (threadIdx.x >= ofs) ? ts[threadIdx.x - ofs] : 0;
        __syncthreads();
        ts[threadIdx.x] += add;
        __syncthreads();
    }
    int excl = (threadIdx.x == 0) ? 0 : ts[threadIdx.x - 1];
    excl += part[blockIdx.x];
#pragma unroll
    for (int j = 0; j < 8; ++j) {
        int idx = base + threadIdx.x * 8 + j;
        if (idx < n) row_start[idx] = excl;
        excl += v[j];
    }
}

// ---- build CSR entries: slot deterministic (k-ascending within row) ----
__global__ void kb_build(const int* __restrict__ gather, const int* __restrict__ scatter,
                         const unsigned* __restrict__ mask, const int* __restrict__ row_start,
                         int* __restrict__ list, int npair, int M)
{
    int p = blockIdx.x * blockDim.x + threadIdx.x;
    int k = blockIdx.y;
    if (p >= npair) return;
    int s = scatter[(size_t)k * npair + p];
    if (s >= M) return;
    int g = gather[(size_t)k * npair + p];
    int slot = row_start[s] + __popc(mask[s] & ((1u << k) - 1u));
    list[slot] = (k << 18) | g;
}

// ---- main: weights in LDS, f16 dot2, half-wave per row, write-once ----
__global__ __launch_bounds__(1024, 8)
void kb_main(const uint4* __restrict__ featH, const uint4* __restrict__ wH,
             const int* __restrict__ row_start, const int* __restrict__ list,
             float* __restrict__ out, int M, int K)
{
    __shared__ uint4 wL[KMAX * 128];                 // 55296 B
    for (int i = threadIdx.x; i < K * 128; i += 1024) wL[i] = wH[i];
    __syncthreads();

    const int lane = threadIdx.x & 31;               // output channel
    int h  = (blockIdx.x * 1024 + threadIdx.x) >> 5;
    int nh = (gridDim.x * 1024) >> 5;
    for (int m = h; m < M; m += nh) {
        int e0 = row_start[m], e1 = row_start[m + 1];
        float a0 = 0.f, a1 = 0.f, a2 = 0.f, a3 = 0.f;
        for (int e = e0; e < e1; ++e) {
            int pk = list[e];
            int k = pk >> 18, g = pk & 0x3FFFF;
            const uint4* fr = featH + ((size_t)g << 2);
            uint4 f0 = fr[0], f1 = fr[1], f2 = fr[2], f3 = fr[3];   // uniform -> broadcast
            const uint4* wr = wL + k * 128 + lane;                   // stride-16B ds_read_b128
            uint4 w0 = wr[0], w1 = wr[32], w2 = wr[64], w3 = wr[96];
            a0 = dot2(f0.x, w0.x, a0); a0 = dot2(f0.y, w0.y, a0);
            a0 = dot2(f0.z, w0.z, a0); a0 = dot2(f0.w, w0.w, a0);
            a1 = dot2(f1.x, w1.x, a1); a1 = dot2(f1.y, w1.y, a1);
            a1 = dot2(f1.z, w1.z, a1); a1 = dot2(f1.w, w1.w, a1);
            a2 = dot2(f2.x, w2.x, a2); a2 = dot2(f2.y, w2.y, a2);
            a2 = dot2(f2.z, w2.z, a2); a2 = dot2(f2.w, w2.w, a2);
            a3 = dot2(f3.x, w3.x, a3); a3 = dot2(f3.y, w3.y, a3);
            a3 = dot2(f3.z, w3.z, a3); a3 = dot2(f3.w, w3.w, a3);
        }
        out[(size_t)m * COUT + lane] = (a0 + a1) + (a2 + a3);
    }
}

// ---- fallback (R1): atomic scatter ----
__global__ __launch_bounds__(256, 4)
void spconv_scatter(const float* __restrict__ feat, const float* __restrict__ weight,
                    const int* __restrict__ gather, const int* __restrict__ scatter,
                    float* __restrict__ out, int npair, int M)
{
    const int k = blockIdx.y;
    const int lane = threadIdx.x & 31;
    const int sub = threadIdx.x >> 5;
    const int pairs_per_blk = blockDim.x >> 5;
    const float* wk = weight + (size_t)k * (CIN * COUT);
    float w[CIN];
#pragma unroll
    for (int i = 0; i < CIN; ++i) w[i] = wk[i * COUT + lane];
    const int* gk = gather + (size_t)k * npair;
    const int* sk = scatter + (size_t)k * npair;
    for (int p = blockIdx.x * pairs_per_blk + sub; p < npair; p += gridDim.x * pairs_per_blk) {
        int s = sk[p];
        if (s >= M) continue;
        int g = gk[p];
        const float4* fr = (const float4*)(feat + (size_t)g * CIN);
        float a = 0.f;
#pragma unroll
        for (int c = 0; c < 8; ++c) {
            float4 f4 = fr[c];
            a = fmaf(f4.x, w[4*c+0], a); a = fmaf(f4.y, w[4*c+1], a);
            a = fmaf(f4.z, w[4*c+2], a); a = fmaf(f4.w, w[4*c+3], a);
        }
        atomicAdd(&out[(size_t)s * COUT + lane], a);
    }
}

extern "C" void kernel_launch(void* const* d_in, const int* in_sizes, int n_in,
                              void* d_out, int out_size, void* d_ws, size_t ws_size,
                              hipStream_t stream)
{
    const float* feat    = (const float*)d_in[0];
    const float* weight  = (const float*)d_in[1];
    const int*   gather  = (const int*)d_in[2];
    const int*   scatter = (const int*)d_in[3];
    float*       out     = (float*)d_out;

    const int N     = in_sizes[0] / CIN;            // 150000 input sites
    const int K     = in_sizes[1] / (CIN * COUT);   // 27
    const int npair = in_sizes[2] / K;              // 150000
    const int M     = out_size / COUT;              // num_out (~2.13M)
    const int NB    = (M + SCAN_B - 1) / SCAN_B;    // scan blocks (~1041)

    // workspace layout
    uintptr_t base = (uintptr_t)d_ws;
    auto align16 = [](uintptr_t p) { return (p + 15) & ~(uintptr_t)15; };
    uintptr_t p_mask = align16(base);                              // M uints
    uintptr_t p_rs   = align16(p_mask + (size_t)M * 4);            // M+1 ints
    uintptr_t p_part = align16(p_rs + ((size_t)M + 1) * 4);        // 2048 ints
    uintptr_t p_wH   = align16(p_part + 2048 * 4);                 // K*512 uints
    uintptr_t p_fH   = align16(p_wH + (size_t)K * 512 * 4);        // N*16 uints
    uintptr_t p_list = align16(p_fH + (size_t)N * 16 * 4);         // K*npair ints
    uintptr_t p_end  = p_list + (size_t)K * npair * 4;

    if (p_end - base > ws_size || NB > 2048 || K > KMAX) {
        hipMemsetAsync(d_out, 0, (size_t)out_size * sizeof(float), stream);
        dim3 grid(160, K);
        spconv_scatter<<<grid, 256, 0, stream>>>(feat, weight, gather, scatter, out, npair, M);
        return;
    }

    unsigned* mask      = (unsigned*)p_mask;
    int*      row_start = (int*)p_rs;
    int*      part      = (int*)p_part;
    unsigned* wH        = (unsigned*)p_wH;
    unsigned* fH        = (unsigned*)p_fH;
    int*      list      = (int*)p_list;

    hipMemsetAsync(mask, 0, (size_t)M * 4, stream);

    kb_pack<<<(K * 512 + 255) / 256, 256, 0, stream>>>(weight, wH, K * 512);
    kf_pack<<<(N * 16 + 255) / 256, 256, 0, stream>>>(feat, fH, N * 16);

    dim3 gp((npair + 255) / 256, K);
    kb_mask<<<gp, 256, 0, stream>>>(scatter, mask, npair, M);

    kb_scan1<<<NB, 256, 0, stream>>>(mask, part, M);
    kb_scan2<<<1, 1024, 0, stream>>>(part, NB, row_start + M);   // also writes total
    kb_scan3<<<NB, 256, 0, stream>>>(mask, part, row_start, M);

    kb_build<<<gp, 256, 0, stream>>>(gather, scatter, mask, row_start, list, npair, M);

    // write-once main: every output row covered, no memset of d_out
    kb_main<<<512, 1024, 0, stream>>>((const uint4*)fH, (const uint4*)wH,
                                      row_start, list, out, M, K);
}